// Round 8
// baseline (284.279 us; speedup 1.0000x reference)
//
#include <hip/hip_runtime.h>
#include <stdint.h>

// MHSA: B=4, S=2048, D=1024, H=16, dk=64. fp32 in/out, bf16 MFMA compute.
//
// Pipeline:
//  k0: cvtAll   fp32 -> bf16 for x + all 4 weights (single launch).
//  k1: gemm<0>  QKV projection; Q output pre-scaled by 0.125*log2(e) so the
//               attention exp argument comes straight from the MFMA acc.
//  k2: transV   V [B,H,S,dk] -> V^T [B,H,dk,S].
//  k3: attn4    S^T = K Q^T flash attention; C-init = -4*log2(e);
//               truncating v_perm bf16 pack; XOR-swizzled LDS (bank-floor on
//               all patterns); double-buffered K/V staging w/ ONE barrier per
//               64-key iter; rowsum via ones-MFMA; O over Q in-place.
//  k4: gemm<1>  output projection, fp32 out.
//
// R7 vs R6: attn3 85.5us @ VALU 42%, Mfma 19.6%, 11.9M bank conflicts ->
// cut per-element VALU (fold scale+shift into MFMA, perm-pack) + swizzle +
// single-barrier dbuf.

typedef __attribute__((ext_vector_type(8))) short short8;
typedef __attribute__((ext_vector_type(4))) short short4v;
typedef __attribute__((ext_vector_type(4))) float float4v;
typedef __attribute__((ext_vector_type(2))) unsigned int uint2v;

#define QSCALE 0.18033688011112042f  // 0.125 * log2(e), folded into Q
#define EXP_C2 5.770780163555852f    // 4 * log2(e), folded into MFMA C-init

__device__ inline short f2bf(float f) {
  union { float f; uint32_t u; } v; v.f = f;
  uint32_t r = (v.u + 0x7fffu + ((v.u >> 16) & 1)) >> 16;
  return (short)(uint16_t)r;
}

// pack 2 f32 -> 2 bf16 (truncating), a -> low short, b -> high short
__device__ inline unsigned int pack2bf(float a, float b) {
  union { float f; unsigned int u; } ua, ub;
  ua.f = a; ub.f = b;
  return __builtin_amdgcn_perm(ub.u, ua.u, 0x07060302u);
}

__device__ inline void async_copy16(const void* g, void* l) {
  __builtin_amdgcn_global_load_lds(
      (const __attribute__((address_space(1))) void*)g,
      (__attribute__((address_space(3))) void*)l, 16, 0, 0);
}

// ---------------------------------------------------------------------------
// fp32 -> bf16: x (8192 blocks) + 4 weights (1024 blocks each) in one launch.
// ---------------------------------------------------------------------------
__global__ __launch_bounds__(256) void cvtAll(
    const float* __restrict__ x, const float* __restrict__ wq,
    const float* __restrict__ wk, const float* __restrict__ wv,
    const float* __restrict__ wo,
    short* __restrict__ xb, short* __restrict__ wqb, short* __restrict__ wkb,
    short* __restrict__ wvb, short* __restrict__ wob) {
  const int b = blockIdx.x;
  const float* s; short* d; int base;
  if (b < 8192) { s = x; d = xb; base = b; }
  else {
    const int wi = (b - 8192) >> 10; base = (b - 8192) & 1023;
    s = (wi == 0) ? wq : (wi == 1) ? wk : (wi == 2) ? wv : wo;
    d = (wi == 0) ? wqb : (wi == 1) ? wkb : (wi == 2) ? wvb : wob;
  }
  const size_t i = (size_t)base * 256 + threadIdx.x;
  const float4v v = *(const float4v*)(s + 4 * i);
  short4v o;
  o[0] = f2bf(v[0]); o[1] = f2bf(v[1]);
  o[2] = f2bf(v[2]); o[3] = f2bf(v[3]);
  *(short4v*)(d + 4 * i) = o;
}

// ---------------------------------------------------------------------------
// GEMM: Y[8192][1024] = A[8192][1024] @ W^T bf16.
// MODE 0: 3 weights via blockIdx.z; Y bf16 [B,H,S,dk]; z==0 (Q) scaled.
// MODE 1: A read through [B,H,S,dk] map; Y fp32 row-major.
// ---------------------------------------------------------------------------
template <int MODE>
__global__ __launch_bounds__(256) void gemm_bt(
    const short* __restrict__ A,
    const short* __restrict__ W0, const short* __restrict__ W1,
    const short* __restrict__ W2,
    short* __restrict__ Yb0, short* __restrict__ Yb1, short* __restrict__ Yb2,
    float* __restrict__ Yf) {
  constexpr int Kd = 1024;
  __shared__ __align__(16) short As[128 * 32];
  __shared__ __align__(16) short Bs[128 * 32];

  const int t = threadIdx.x;
  const int w = t >> 6, l = t & 63, l15 = l & 15, quad = l >> 4;
  const int wm = w >> 1, wn = w & 1;
  const int m0 = blockIdx.y * 128, n0 = blockIdx.x * 128;

  const short* W = W0;
  short* Yb = Yb0;
  float sc = 1.0f;
  if (MODE == 0) {
    if (blockIdx.z == 0) sc = QSCALE;
    else if (blockIdx.z == 1) { W = W1; Yb = Yb1; }
    else { W = W2; Yb = Yb2; }
  }

  float4v acc[4][4];
#pragma unroll
  for (int i = 0; i < 4; i++)
#pragma unroll
    for (int j = 0; j < 4; j++) acc[i][j] = (float4v){0.f, 0.f, 0.f, 0.f};

  const int r4 = t >> 2, c48 = (t & 3) * 8;
  const short* Wbase = W + (n0 + r4) * Kd + c48;
  short* AsW = &As[w * 512];
  short* BsW = &Bs[w * 512];
  const int i0 = m0 + r4;
  const int i1 = m0 + 64 + r4;

  for (int k0 = 0; k0 < Kd; k0 += 32) {
    if (MODE == 0) {
      async_copy16(A + (size_t)i0 * Kd + k0 + c48, AsW);
      async_copy16(A + (size_t)i1 * Kd + k0 + c48, AsW + 2048);
    } else {
      const int k = k0 + c48, h = k >> 6, dd = k & 63;
      async_copy16(A + ((((size_t)(i0 >> 11) * 16 + h) * 2048 + (i0 & 2047)) * 64 + dd), AsW);
      async_copy16(A + ((((size_t)(i1 >> 11) * 16 + h) * 2048 + (i1 & 2047)) * 64 + dd), AsW + 2048);
    }
    async_copy16(Wbase + k0, BsW);
    async_copy16(Wbase + 64 * Kd + k0, BsW + 2048);
    __syncthreads();
    short8 af[4], bf[4];
#pragma unroll
    for (int mi = 0; mi < 4; mi++)
      af[mi] = *(const short8*)&As[(wm * 64 + mi * 16 + l15) * 32 + quad * 8];
#pragma unroll
    for (int ni = 0; ni < 4; ni++)
      bf[ni] = *(const short8*)&Bs[(wn * 64 + ni * 16 + l15) * 32 + quad * 8];
#pragma unroll
    for (int mi = 0; mi < 4; mi++)
#pragma unroll
      for (int ni = 0; ni < 4; ni++)
        acc[mi][ni] = __builtin_amdgcn_mfma_f32_16x16x32_bf16(
            af[mi], bf[ni], acc[mi][ni], 0, 0, 0);
    __syncthreads();
  }

#pragma unroll
  for (int mi = 0; mi < 4; mi++) {
    const int ib = m0 + wm * 64 + mi * 16 + quad * 4;
#pragma unroll
    for (int ni = 0; ni < 4; ni++) {
      const int j = n0 + wn * 64 + ni * 16 + l15;
#pragma unroll
      for (int r = 0; r < 4; r++) {
        const int i = ib + r;
        if (MODE == 0) {
          Yb[((((size_t)(i >> 11) * 16 + (j >> 6)) * 2048 + (i & 2047)) * 64 + (j & 63))] =
              f2bf(acc[mi][ni][r] * sc);
        } else {
          Yf[(size_t)i * 1024 + j] = acc[mi][ni][r];
        }
      }
    }
  }
}

// ---------------------------------------------------------------------------
// V transpose: [B,H,S,dk] -> [B,H,dk,S].
// ---------------------------------------------------------------------------
__global__ __launch_bounds__(256) void transV(const short* __restrict__ V,
                                              short* __restrict__ VT) {
  __shared__ __align__(16) short Ls[64 * 72];
  const int t = threadIdx.x;
  const int s0 = blockIdx.x * 64, bh = blockIdx.y;
  const short* Vh = V + (size_t)bh * 2048 * 64;
  short* Th = VT + (size_t)bh * 64 * 2048;
  const int r = t >> 2, c = (t & 3) * 16;
  *(short8*)&Ls[r * 72 + c] = *(const short8*)&Vh[(size_t)(s0 + r) * 64 + c];
  *(short8*)&Ls[r * 72 + c + 8] = *(const short8*)&Vh[(size_t)(s0 + r) * 64 + c + 8];
  __syncthreads();
  short8 o0, o1;
#pragma unroll
  for (int j = 0; j < 8; j++) {
    o0[j] = Ls[(c + j) * 72 + r];
    o1[j] = Ls[(c + 8 + j) * 72 + r];
  }
  *(short8*)&Th[(size_t)r * 2048 + s0 + c] = o0;
  *(short8*)&Th[(size_t)r * 2048 + s0 + c + 8] = o1;
}

// ---------------------------------------------------------------------------
// Flash attention v4. grid (16,64), 256 thr = 4 waves, 16 q/wave.
// Paired q-tiles (bx, 31-bx). XOR-swizzled LDS rows of 64 shorts
// (16B chunk c of row r lives at chunk c^(r&7)). Double-buffered K/V,
// one __syncthreads per 64-key iter.
// ---------------------------------------------------------------------------
__global__ __launch_bounds__(256) void attn4(
    short* __restrict__ Q,          // [B,H,S,dk] in, O out
    const short* __restrict__ K,    // [B,H,S,dk]
    const short* __restrict__ VT) { // [B,H,dk,S]
  __shared__ __align__(16) short Ks[2][64 * 64];
  __shared__ __align__(16) short Vs[2][64 * 64];
  __shared__ __align__(16) short Ps[4][16 * 64];

  const int t = threadIdx.x;
  const int w = t >> 6, l = t & 63, l15 = l & 15, quad = l >> 4;
  const int bh = blockIdx.y;
  short* Qh = Q + (size_t)bh * 2048 * 64;
  const short* Kh = K + (size_t)bh * 2048 * 64;
  const short* Vh = VT + (size_t)bh * 64 * 2048;

  // staging: thread t covers row sr (0..63), short-chunks 2c0, 2c0+1
  const int sr = t >> 2, c0 = t & 3;
  const int ssw = sr & 7;
  const int stA = sr * 64 + (((2 * c0) ^ ssw) << 3);      // swizzled offsets
  const int stB = sr * 64 + (((2 * c0 + 1) ^ ssw) << 3);
  const int gA = c0 * 16, gB = c0 * 16 + 8;               // global chunks

  // fragment chunk swizzle key
  const int fsw = l15 & 7;
  const int fc0 = (quad ^ fsw) << 3;        // chunk quad
  const int fc1 = ((4 + quad) ^ fsw) << 3;  // chunk 4+quad
  short* PsW = &Ps[w][0];
  const int pwr = l15 * 64;  // P row base (row = q = l15)

  short8 ones;
#pragma unroll
  for (int j = 0; j < 8; j++) ones[j] = (short)0x3F80;
  const float4v initC = (float4v){-EXP_C2, -EXP_C2, -EXP_C2, -EXP_C2};

  for (int pass = 0; pass < 2; pass++) {
    const int q0 = (pass ? (31 - blockIdx.x) : blockIdx.x) * 64;
    const int qn = q0 + w * 16 + l15;
    const short8 qf0 = *(const short8*)&Qh[(size_t)qn * 64 + quad * 8];
    const short8 qf1 = *(const short8*)&Qh[(size_t)qn * 64 + 32 + quad * 8];

    float4v acc[4];
#pragma unroll
    for (int dt = 0; dt < 4; dt++) acc[dt] = (float4v){0.f, 0.f, 0.f, 0.f};
    float4v accL = (float4v){0.f, 0.f, 0.f, 0.f};

    // prologue: kb=0 tiles to regs
    short8 kv0 = *(const short8*)&Kh[(size_t)sr * 64 + gA];
    short8 kv1 = *(const short8*)&Kh[(size_t)sr * 64 + gB];
    short8 vv0 = *(const short8*)&Vh[(size_t)sr * 2048 + gA];
    short8 vv1 = *(const short8*)&Vh[(size_t)sr * 2048 + gB];

    int p = 0;
    for (int kb = 0; kb <= q0; kb += 64, p ^= 1) {
      const bool diag = (kb == q0);
      short* KsP = &Ks[p][0];
      short* VsP = &Vs[p][0];
      *(short8*)&KsP[stA] = kv0;
      *(short8*)&KsP[stB] = kv1;
      *(short8*)&VsP[stA] = vv0;
      *(short8*)&VsP[stB] = vv1;
      __syncthreads();

      // prefetch next k-block (redundant reload on last iter)
      const int kb2 = diag ? kb : kb + 64;
      kv0 = *(const short8*)&Kh[(size_t)(kb2 + sr) * 64 + gA];
      kv1 = *(const short8*)&Kh[(size_t)(kb2 + sr) * 64 + gB];
      vv0 = *(const short8*)&Vh[(size_t)sr * 2048 + kb2 + gA];
      vv1 = *(const short8*)&Vh[(size_t)sr * 2048 + kb2 + gB];

      // S^T = K Q^T ; exp arg = acc directly (Q pre-scaled, C-init = -C2)
#pragma unroll
      for (int kt = 0; kt < 4; kt++) {
        const int krb = (kt * 16 + l15) * 64;
        const short8 kf0 = *(const short8*)&KsP[krb + fc0];
        const short8 kf1 = *(const short8*)&KsP[krb + fc1];
        float4v s = __builtin_amdgcn_mfma_f32_16x16x32_bf16(kf0, qf0, initC, 0, 0, 0);
        s = __builtin_amdgcn_mfma_f32_16x16x32_bf16(kf1, qf1, s, 0, 0, 0);
        float p0 = __builtin_amdgcn_exp2f(s[0]);
        float p1 = __builtin_amdgcn_exp2f(s[1]);
        float p2 = __builtin_amdgcn_exp2f(s[2]);
        float p3 = __builtin_amdgcn_exp2f(s[3]);
        if (diag) {
          const int key = kb + kt * 16 + quad * 4;
          p0 = (key <= qn) ? p0 : 0.f;
          p1 = (key + 1 <= qn) ? p1 : 0.f;
          p2 = (key + 2 <= qn) ? p2 : 0.f;
          p3 = (key + 3 <= qn) ? p3 : 0.f;
        }
        uint2v pw;
        pw[0] = pack2bf(p0, p1);
        pw[1] = pack2bf(p2, p3);
        // P[q=l15][key chunk 2kt+(quad>>1), half quad&1], swizzled
        *(uint2v*)&PsW[pwr + (((2 * kt + (quad >> 1)) ^ fsw) << 3) +
                       ((quad & 1) << 2)] = pw;
      }
      __builtin_amdgcn_wave_barrier();

      // O^T += V^T P^T ; l += 1 P^T
      const short8 pf0 = *(const short8*)&PsW[pwr + fc0];
      const short8 pf1 = *(const short8*)&PsW[pwr + fc1];
#pragma unroll
      for (int dt = 0; dt < 4; dt++) {
        const int vrb = (dt * 16 + l15) * 64;
        const short8 vf0 = *(const short8*)&VsP[vrb + fc0];
        const short8 vf1 = *(const short8*)&VsP[vrb + fc1];
        acc[dt] = __builtin_amdgcn_mfma_f32_16x16x32_bf16(vf0, pf0, acc[dt], 0, 0, 0);
        acc[dt] = __builtin_amdgcn_mfma_f32_16x16x32_bf16(vf1, pf1, acc[dt], 0, 0, 0);
      }
      accL = __builtin_amdgcn_mfma_f32_16x16x32_bf16(ones, pf0, accL, 0, 0, 0);
      accL = __builtin_amdgcn_mfma_f32_16x16x32_bf16(ones, pf1, accL, 0, 0, 0);
    }

    const float inv = 1.0f / fmaxf(accL[0], 1e-30f);
#pragma unroll
    for (int dt = 0; dt < 4; dt++) {
      short4v o;
#pragma unroll
      for (int ri = 0; ri < 4; ri++) o[ri] = f2bf(acc[dt][ri] * inv);
      *(short4v*)&Qh[(size_t)qn * 64 + dt * 16 + quad * 4] = o;
    }
    if (pass == 0) __syncthreads();  // re-align barrier counts across waves
  }
}

extern "C" void kernel_launch(void* const* d_in, const int* in_sizes, int n_in,
                              void* d_out, int out_size, void* d_ws,
                              size_t ws_size, hipStream_t stream) {
  const float* x = (const float*)d_in[0];
  const float* wq = (const float*)d_in[1];
  const float* wk = (const float*)d_in[2];
  const float* wv = (const float*)d_in[3];
  const float* wo = (const float*)d_in[4];
  float* out = (float*)d_out;

  // d_out scratch (32 MB, dead until k4 overwrites it fully)
  short* xb = (short*)d_out;                 // bf16 x (16 MB)
  short* vtg = xb + (size_t)8192 * 1024;     // V^T (16 MB)

  // d_ws (bf16): 56 MB total
  short* wqb = (short*)d_ws;
  short* wkb = wqb + (size_t)1024 * 1024;
  short* wvb = wkb + (size_t)1024 * 1024;
  short* wob = wvb + (size_t)1024 * 1024;
  short* qws = wob + (size_t)1024 * 1024;    // [B,H,S,dk], O in-place
  short* kws = qws + (size_t)8192 * 1024;
  short* vws = kws + (size_t)8192 * 1024;

  cvtAll<<<12288, 256, 0, stream>>>(x, wq, wk, wv, wo, xb, wqb, wkb, wvb, wob);
  gemm_bt<0><<<dim3(8, 64, 3), 256, 0, stream>>>(
      xb, wqb, wkb, wvb, qws, kws, vws, nullptr);
  transV<<<dim3(32, 64), 256, 0, stream>>>(vws, vtg);
  attn4<<<dim3(16, 64), 256, 0, stream>>>(qws, kws, vtg);
  gemm_bt<1><<<dim3(8, 64, 1), 256, 0, stream>>>(
      qws, wob, nullptr, nullptr, nullptr, nullptr, nullptr, out);
}

// Round 9
// 259.369 us; speedup vs baseline: 1.0960x; 1.0960x over previous
//
#include <hip/hip_runtime.h>
#include <stdint.h>

// MHSA: B=4, S=2048, D=1024, H=16, dk=64. fp32 in/out, bf16 MFMA compute.
//
// Pipeline:
//  k0: cvtAll   fp32 -> bf16 for x + all 4 weights (single launch).
//  k1: gemm<0>  QKV projection; Q pre-scaled by 0.125*log2(e).
//  k2: transV   V [B,H,S,dk] -> V^T [B,H,dk,S].
//  k3: attn4    S^T = K Q^T flash attention; C-init = -4*log2(e);
//               v_perm bf16 pack; XOR-swizzled LDS; double-buffered K/V,
//               one barrier/iter; rowsum via ones-MFMA; O over Q in-place.
//               R8: XCD-aware grid: blockIdx.x = bh (64), blockIdx.y = q-pair
//               (16). linear id = bh + 64*qp => id%8 = bh%8 => all 16 blocks
//               of one head share an XCD/L2 -> K/V re-reads become L2 hits.
//               (R5-R7: 257 MB FETCH @3.3 TB/s = 78us ~= whole kernel; three
//               different compute structures all pinned at 85us = fetch-bound.)
//  k4: gemm<1>  output projection, fp32 out.

typedef __attribute__((ext_vector_type(8))) short short8;
typedef __attribute__((ext_vector_type(4))) short short4v;
typedef __attribute__((ext_vector_type(4))) float float4v;
typedef __attribute__((ext_vector_type(2))) unsigned int uint2v;

#define QSCALE 0.18033688011112042f  // 0.125 * log2(e), folded into Q
#define EXP_C2 5.770780163555852f    // 4 * log2(e), folded into MFMA C-init

__device__ inline short f2bf(float f) {
  union { float f; uint32_t u; } v; v.f = f;
  uint32_t r = (v.u + 0x7fffu + ((v.u >> 16) & 1)) >> 16;
  return (short)(uint16_t)r;
}

// pack 2 f32 -> 2 bf16 (truncating), a -> low short, b -> high short
__device__ inline unsigned int pack2bf(float a, float b) {
  union { float f; unsigned int u; } ua, ub;
  ua.f = a; ub.f = b;
  return __builtin_amdgcn_perm(ub.u, ua.u, 0x07060302u);
}

__device__ inline void async_copy16(const void* g, void* l) {
  __builtin_amdgcn_global_load_lds(
      (const __attribute__((address_space(1))) void*)g,
      (__attribute__((address_space(3))) void*)l, 16, 0, 0);
}

// ---------------------------------------------------------------------------
// fp32 -> bf16: x (8192 blocks) + 4 weights (1024 blocks each) in one launch.
// ---------------------------------------------------------------------------
__global__ __launch_bounds__(256) void cvtAll(
    const float* __restrict__ x, const float* __restrict__ wq,
    const float* __restrict__ wk, const float* __restrict__ wv,
    const float* __restrict__ wo,
    short* __restrict__ xb, short* __restrict__ wqb, short* __restrict__ wkb,
    short* __restrict__ wvb, short* __restrict__ wob) {
  const int b = blockIdx.x;
  const float* s; short* d; int base;
  if (b < 8192) { s = x; d = xb; base = b; }
  else {
    const int wi = (b - 8192) >> 10; base = (b - 8192) & 1023;
    s = (wi == 0) ? wq : (wi == 1) ? wk : (wi == 2) ? wv : wo;
    d = (wi == 0) ? wqb : (wi == 1) ? wkb : (wi == 2) ? wvb : wob;
  }
  const size_t i = (size_t)base * 256 + threadIdx.x;
  const float4v v = *(const float4v*)(s + 4 * i);
  short4v o;
  o[0] = f2bf(v[0]); o[1] = f2bf(v[1]);
  o[2] = f2bf(v[2]); o[3] = f2bf(v[3]);
  *(short4v*)(d + 4 * i) = o;
}

// ---------------------------------------------------------------------------
// GEMM: Y[8192][1024] = A[8192][1024] @ W^T bf16.
// MODE 0: 3 weights via blockIdx.z; Y bf16 [B,H,S,dk]; z==0 (Q) scaled.
// MODE 1: A read through [B,H,S,dk] map; Y fp32 row-major.
// ---------------------------------------------------------------------------
template <int MODE>
__global__ __launch_bounds__(256) void gemm_bt(
    const short* __restrict__ A,
    const short* __restrict__ W0, const short* __restrict__ W1,
    const short* __restrict__ W2,
    short* __restrict__ Yb0, short* __restrict__ Yb1, short* __restrict__ Yb2,
    float* __restrict__ Yf) {
  constexpr int Kd = 1024;
  __shared__ __align__(16) short As[128 * 32];
  __shared__ __align__(16) short Bs[128 * 32];

  const int t = threadIdx.x;
  const int w = t >> 6, l = t & 63, l15 = l & 15, quad = l >> 4;
  const int wm = w >> 1, wn = w & 1;
  const int m0 = blockIdx.y * 128, n0 = blockIdx.x * 128;

  const short* W = W0;
  short* Yb = Yb0;
  float sc = 1.0f;
  if (MODE == 0) {
    if (blockIdx.z == 0) sc = QSCALE;
    else if (blockIdx.z == 1) { W = W1; Yb = Yb1; }
    else { W = W2; Yb = Yb2; }
  }

  float4v acc[4][4];
#pragma unroll
  for (int i = 0; i < 4; i++)
#pragma unroll
    for (int j = 0; j < 4; j++) acc[i][j] = (float4v){0.f, 0.f, 0.f, 0.f};

  const int r4 = t >> 2, c48 = (t & 3) * 8;
  const short* Wbase = W + (n0 + r4) * Kd + c48;
  short* AsW = &As[w * 512];
  short* BsW = &Bs[w * 512];
  const int i0 = m0 + r4;
  const int i1 = m0 + 64 + r4;

  for (int k0 = 0; k0 < Kd; k0 += 32) {
    if (MODE == 0) {
      async_copy16(A + (size_t)i0 * Kd + k0 + c48, AsW);
      async_copy16(A + (size_t)i1 * Kd + k0 + c48, AsW + 2048);
    } else {
      const int k = k0 + c48, h = k >> 6, dd = k & 63;
      async_copy16(A + ((((size_t)(i0 >> 11) * 16 + h) * 2048 + (i0 & 2047)) * 64 + dd), AsW);
      async_copy16(A + ((((size_t)(i1 >> 11) * 16 + h) * 2048 + (i1 & 2047)) * 64 + dd), AsW + 2048);
    }
    async_copy16(Wbase + k0, BsW);
    async_copy16(Wbase + 64 * Kd + k0, BsW + 2048);
    __syncthreads();
    short8 af[4], bf[4];
#pragma unroll
    for (int mi = 0; mi < 4; mi++)
      af[mi] = *(const short8*)&As[(wm * 64 + mi * 16 + l15) * 32 + quad * 8];
#pragma unroll
    for (int ni = 0; ni < 4; ni++)
      bf[ni] = *(const short8*)&Bs[(wn * 64 + ni * 16 + l15) * 32 + quad * 8];
#pragma unroll
    for (int mi = 0; mi < 4; mi++)
#pragma unroll
      for (int ni = 0; ni < 4; ni++)
        acc[mi][ni] = __builtin_amdgcn_mfma_f32_16x16x32_bf16(
            af[mi], bf[ni], acc[mi][ni], 0, 0, 0);
    __syncthreads();
  }

#pragma unroll
  for (int mi = 0; mi < 4; mi++) {
    const int ib = m0 + wm * 64 + mi * 16 + quad * 4;
#pragma unroll
    for (int ni = 0; ni < 4; ni++) {
      const int j = n0 + wn * 64 + ni * 16 + l15;
#pragma unroll
      for (int r = 0; r < 4; r++) {
        const int i = ib + r;
        if (MODE == 0) {
          Yb[((((size_t)(i >> 11) * 16 + (j >> 6)) * 2048 + (i & 2047)) * 64 + (j & 63))] =
              f2bf(acc[mi][ni][r] * sc);
        } else {
          Yf[(size_t)i * 1024 + j] = acc[mi][ni][r];
        }
      }
    }
  }
}

// ---------------------------------------------------------------------------
// V transpose: [B,H,S,dk] -> [B,H,dk,S].
// ---------------------------------------------------------------------------
__global__ __launch_bounds__(256) void transV(const short* __restrict__ V,
                                              short* __restrict__ VT) {
  __shared__ __align__(16) short Ls[64 * 72];
  const int t = threadIdx.x;
  const int s0 = blockIdx.x * 64, bh = blockIdx.y;
  const short* Vh = V + (size_t)bh * 2048 * 64;
  short* Th = VT + (size_t)bh * 64 * 2048;
  const int r = t >> 2, c = (t & 3) * 16;
  *(short8*)&Ls[r * 72 + c] = *(const short8*)&Vh[(size_t)(s0 + r) * 64 + c];
  *(short8*)&Ls[r * 72 + c + 8] = *(const short8*)&Vh[(size_t)(s0 + r) * 64 + c + 8];
  __syncthreads();
  short8 o0, o1;
#pragma unroll
  for (int j = 0; j < 8; j++) {
    o0[j] = Ls[(c + j) * 72 + r];
    o1[j] = Ls[(c + 8 + j) * 72 + r];
  }
  *(short8*)&Th[(size_t)r * 2048 + s0 + c] = o0;
  *(short8*)&Th[(size_t)r * 2048 + s0 + c + 8] = o1;
}

// ---------------------------------------------------------------------------
// Flash attention v4 + XCD swizzle. grid (64 bh, 16 qp), 256 thr = 4 waves.
// Paired q-tiles (qp, 31-qp). XOR-swizzled LDS rows of 64 shorts.
// Double-buffered K/V, one __syncthreads per 64-key iter.
// ---------------------------------------------------------------------------
__global__ __launch_bounds__(256) void attn4(
    short* __restrict__ Q,          // [B,H,S,dk] in, O out
    const short* __restrict__ K,    // [B,H,S,dk]
    const short* __restrict__ VT) { // [B,H,dk,S]
  __shared__ __align__(16) short Ks[2][64 * 64];
  __shared__ __align__(16) short Vs[2][64 * 64];
  __shared__ __align__(16) short Ps[4][16 * 64];

  const int t = threadIdx.x;
  const int w = t >> 6, l = t & 63, l15 = l & 15, quad = l >> 4;
  const int bh = blockIdx.x;   // R8: bh on x => id%8 = bh%8 => per-head XCD
  const int qp = blockIdx.y;   // q-pair index 0..15
  short* Qh = Q + (size_t)bh * 2048 * 64;
  const short* Kh = K + (size_t)bh * 2048 * 64;
  const short* Vh = VT + (size_t)bh * 64 * 2048;

  // staging: thread t covers row sr (0..63), short-chunks 2c0, 2c0+1
  const int sr = t >> 2, c0 = t & 3;
  const int ssw = sr & 7;
  const int stA = sr * 64 + (((2 * c0) ^ ssw) << 3);
  const int stB = sr * 64 + (((2 * c0 + 1) ^ ssw) << 3);
  const int gA = c0 * 16, gB = c0 * 16 + 8;

  // fragment chunk swizzle key
  const int fsw = l15 & 7;
  const int fc0 = (quad ^ fsw) << 3;
  const int fc1 = ((4 + quad) ^ fsw) << 3;
  short* PsW = &Ps[w][0];
  const int pwr = l15 * 64;

  short8 ones;
#pragma unroll
  for (int j = 0; j < 8; j++) ones[j] = (short)0x3F80;
  const float4v initC = (float4v){-EXP_C2, -EXP_C2, -EXP_C2, -EXP_C2};

  for (int pass = 0; pass < 2; pass++) {
    const int q0 = (pass ? (31 - qp) : qp) * 64;
    const int qn = q0 + w * 16 + l15;
    const short8 qf0 = *(const short8*)&Qh[(size_t)qn * 64 + quad * 8];
    const short8 qf1 = *(const short8*)&Qh[(size_t)qn * 64 + 32 + quad * 8];

    float4v acc[4];
#pragma unroll
    for (int dt = 0; dt < 4; dt++) acc[dt] = (float4v){0.f, 0.f, 0.f, 0.f};
    float4v accL = (float4v){0.f, 0.f, 0.f, 0.f};

    // prologue: kb=0 tiles to regs
    short8 kv0 = *(const short8*)&Kh[(size_t)sr * 64 + gA];
    short8 kv1 = *(const short8*)&Kh[(size_t)sr * 64 + gB];
    short8 vv0 = *(const short8*)&Vh[(size_t)sr * 2048 + gA];
    short8 vv1 = *(const short8*)&Vh[(size_t)sr * 2048 + gB];

    int p = 0;
    for (int kb = 0; kb <= q0; kb += 64, p ^= 1) {
      const bool diag = (kb == q0);
      short* KsP = &Ks[p][0];
      short* VsP = &Vs[p][0];
      *(short8*)&KsP[stA] = kv0;
      *(short8*)&KsP[stB] = kv1;
      *(short8*)&VsP[stA] = vv0;
      *(short8*)&VsP[stB] = vv1;
      __syncthreads();

      // prefetch next k-block (redundant reload on last iter)
      const int kb2 = diag ? kb : kb + 64;
      kv0 = *(const short8*)&Kh[(size_t)(kb2 + sr) * 64 + gA];
      kv1 = *(const short8*)&Kh[(size_t)(kb2 + sr) * 64 + gB];
      vv0 = *(const short8*)&Vh[(size_t)sr * 2048 + kb2 + gA];
      vv1 = *(const short8*)&Vh[(size_t)sr * 2048 + kb2 + gB];

      // S^T = K Q^T ; exp arg = acc directly (Q pre-scaled, C-init = -C2)
#pragma unroll
      for (int kt = 0; kt < 4; kt++) {
        const int krb = (kt * 16 + l15) * 64;
        const short8 kf0 = *(const short8*)&KsP[krb + fc0];
        const short8 kf1 = *(const short8*)&KsP[krb + fc1];
        float4v s = __builtin_amdgcn_mfma_f32_16x16x32_bf16(kf0, qf0, initC, 0, 0, 0);
        s = __builtin_amdgcn_mfma_f32_16x16x32_bf16(kf1, qf1, s, 0, 0, 0);
        float p0 = __builtin_amdgcn_exp2f(s[0]);
        float p1 = __builtin_amdgcn_exp2f(s[1]);
        float p2 = __builtin_amdgcn_exp2f(s[2]);
        float p3 = __builtin_amdgcn_exp2f(s[3]);
        if (diag) {
          const int key = kb + kt * 16 + quad * 4;
          p0 = (key <= qn) ? p0 : 0.f;
          p1 = (key + 1 <= qn) ? p1 : 0.f;
          p2 = (key + 2 <= qn) ? p2 : 0.f;
          p3 = (key + 3 <= qn) ? p3 : 0.f;
        }
        uint2v pw;
        pw[0] = pack2bf(p0, p1);
        pw[1] = pack2bf(p2, p3);
        *(uint2v*)&PsW[pwr + (((2 * kt + (quad >> 1)) ^ fsw) << 3) +
                       ((quad & 1) << 2)] = pw;
      }
      __builtin_amdgcn_wave_barrier();

      // O^T += V^T P^T ; l += 1 P^T
      const short8 pf0 = *(const short8*)&PsW[pwr + fc0];
      const short8 pf1 = *(const short8*)&PsW[pwr + fc1];
#pragma unroll
      for (int dt = 0; dt < 4; dt++) {
        const int vrb = (dt * 16 + l15) * 64;
        const short8 vf0 = *(const short8*)&VsP[vrb + fc0];
        const short8 vf1 = *(const short8*)&VsP[vrb + fc1];
        acc[dt] = __builtin_amdgcn_mfma_f32_16x16x32_bf16(vf0, pf0, acc[dt], 0, 0, 0);
        acc[dt] = __builtin_amdgcn_mfma_f32_16x16x32_bf16(vf1, pf1, acc[dt], 0, 0, 0);
      }
      accL = __builtin_amdgcn_mfma_f32_16x16x32_bf16(ones, pf0, accL, 0, 0, 0);
      accL = __builtin_amdgcn_mfma_f32_16x16x32_bf16(ones, pf1, accL, 0, 0, 0);
    }

    const float inv = 1.0f / fmaxf(accL[0], 1e-30f);
#pragma unroll
    for (int dt = 0; dt < 4; dt++) {
      short4v o;
#pragma unroll
      for (int ri = 0; ri < 4; ri++) o[ri] = f2bf(acc[dt][ri] * inv);
      *(short4v*)&Qh[(size_t)qn * 64 + dt * 16 + quad * 4] = o;
    }
    if (pass == 0) __syncthreads();  // re-align barrier counts across waves
  }
}

extern "C" void kernel_launch(void* const* d_in, const int* in_sizes, int n_in,
                              void* d_out, int out_size, void* d_ws,
                              size_t ws_size, hipStream_t stream) {
  const float* x = (const float*)d_in[0];
  const float* wq = (const float*)d_in[1];
  const float* wk = (const float*)d_in[2];
  const float* wv = (const float*)d_in[3];
  const float* wo = (const float*)d_in[4];
  float* out = (float*)d_out;

  // d_out scratch (32 MB, dead until k4 overwrites it fully)
  short* xb = (short*)d_out;                 // bf16 x (16 MB)
  short* vtg = xb + (size_t)8192 * 1024;     // V^T (16 MB)

  // d_ws (bf16): 56 MB total
  short* wqb = (short*)d_ws;
  short* wkb = wqb + (size_t)1024 * 1024;
  short* wvb = wkb + (size_t)1024 * 1024;
  short* wob = wvb + (size_t)1024 * 1024;
  short* qws = wob + (size_t)1024 * 1024;    // [B,H,S,dk], O in-place
  short* kws = qws + (size_t)8192 * 1024;
  short* vws = kws + (size_t)8192 * 1024;

  cvtAll<<<12288, 256, 0, stream>>>(x, wq, wk, wv, wo, xb, wqb, wkb, wvb, wob);
  gemm_bt<0><<<dim3(8, 64, 3), 256, 0, stream>>>(
      xb, wqb, wkb, wvb, qws, kws, vws, nullptr);
  transV<<<dim3(32, 64), 256, 0, stream>>>(vws, vtg);
  attn4<<<dim3(64, 16), 256, 0, stream>>>(qws, kws, vtg);
  gemm_bt<1><<<dim3(8, 64, 1), 256, 0, stream>>>(
      qws, wob, nullptr, nullptr, nullptr, nullptr, nullptr, out);
}